// Round 1
// baseline (211.498 us; speedup 1.0000x reference)
//
#include <hip/hip_runtime.h>

// Haar forward: input (B=8, C=64, H=512, W=512) fp32 NCHW
// output (B, 4, C, H/2, W/2) flattened as (B, 4*C, h, w), subband-major.
// Subbands per 2x2 block {a=x[2i,2j], b=x[2i,2j+1], c=x[2i+1,2j], d=x[2i+1,2j+1]}:
//   LL = .25*(a+b+c+d)   k=0
//   k1 = .25*(a-b+c-d)
//   k2 = .25*(a+b-c-d)
//   k3 = .25*(a-b-c+d)

constexpr int B  = 8;
constexpr int C  = 64;
constexpr int H  = 512;
constexpr int W  = 512;
constexpr int HO = H / 2;   // 256
constexpr int WO = W / 2;   // 256
constexpr int W4 = WO / 4;  // 64 float4-chunks per output row

__global__ __launch_bounds__(256) void haar_fwd(const float* __restrict__ x,
                                                float* __restrict__ y) {
    const int total = B * C * HO * W4;
    int idx = blockIdx.x * blockDim.x + threadIdx.x;
    if (idx >= total) return;

    const int j4 = idx % W4;
    int t = idx / W4;
    const int i = t % HO;
    t /= HO;
    const int c = t % C;
    const int b = t / C;

    // Input: two rows, 8 consecutive floats each (2 x float4), 16B-aligned.
    const float* r0 = x + (((size_t)(b * C + c) * H + 2 * i) * W + 8 * (size_t)j4);
    const float* r1 = r0 + W;
    const float4 r0a = *reinterpret_cast<const float4*>(r0);
    const float4 r0b = *reinterpret_cast<const float4*>(r0 + 4);
    const float4 r1a = *reinterpret_cast<const float4*>(r1);
    const float4 r1b = *reinterpret_cast<const float4*>(r1 + 4);

    // Pixel p: a=row0[2p], bb=row0[2p+1], cc=row1[2p], dd=row1[2p+1]
    const float a0 = r0a.x, b0 = r0a.y, a1 = r0a.z, b1 = r0a.w;
    const float a2 = r0b.x, b2 = r0b.y, a3 = r0b.z, b3 = r0b.w;
    const float c0 = r1a.x, d0 = r1a.y, c1 = r1a.z, d1 = r1a.w;
    const float c2 = r1b.x, d2 = r1b.y, c3 = r1b.z, d3 = r1b.w;

    float4 ll, k1, k2, k3;
    ll.x = 0.25f * (a0 + b0 + c0 + d0);
    ll.y = 0.25f * (a1 + b1 + c1 + d1);
    ll.z = 0.25f * (a2 + b2 + c2 + d2);
    ll.w = 0.25f * (a3 + b3 + c3 + d3);

    k1.x = 0.25f * (a0 - b0 + c0 - d0);
    k1.y = 0.25f * (a1 - b1 + c1 - d1);
    k1.z = 0.25f * (a2 - b2 + c2 - d2);
    k1.w = 0.25f * (a3 - b3 + c3 - d3);

    k2.x = 0.25f * (a0 + b0 - c0 - d0);
    k2.y = 0.25f * (a1 + b1 - c1 - d1);
    k2.z = 0.25f * (a2 + b2 - c2 - d2);
    k2.w = 0.25f * (a3 + b3 - c3 - d3);

    k3.x = 0.25f * (a0 - b0 - c0 + d0);
    k3.y = 0.25f * (a1 - b1 - c1 + d1);
    k3.z = 0.25f * (a2 - b2 - c2 + d2);
    k3.w = 0.25f * (a3 - b3 - c3 + d3);

    // Output: ((b*4 + k)*C + c) plane, row i, cols 4*j4..4*j4+3
    const size_t plane = (size_t)HO * WO;
    const size_t rowoff = (size_t)i * WO + 4 * (size_t)j4;
    float* ybase = y + ((size_t)b * 4 * C + c) * plane + rowoff;

    *reinterpret_cast<float4*>(ybase)                      = ll;
    *reinterpret_cast<float4*>(ybase + (size_t)C * plane)      = k1;
    *reinterpret_cast<float4*>(ybase + (size_t)2 * C * plane)  = k2;
    *reinterpret_cast<float4*>(ybase + (size_t)3 * C * plane)  = k3;
}

extern "C" void kernel_launch(void* const* d_in, const int* in_sizes, int n_in,
                              void* d_out, int out_size, void* d_ws, size_t ws_size,
                              hipStream_t stream) {
    const float* x = (const float*)d_in[0];
    float* y = (float*)d_out;

    const int total = B * C * HO * W4;        // 8,388,608 threads
    const int threads = 256;
    const int blocks = (total + threads - 1) / threads;
    haar_fwd<<<blocks, threads, 0, stream>>>(x, y);
}